// Round 19
// baseline (56.106 us; speedup 1.0000x reference)
//
#include <hip/hip_runtime.h>

#define TOTAL     4194304
#define DIM       32
#define NTOK      (TOTAL / DIM)   // 131072 tokens
#define NCODE     1024
#define CCODES    128             // codes per chunk (8 chunks) -- small LDS for 8 blk/CU
#define DELTA_EPS 2e-3f
#define FLAGBIT   0x40000000

typedef _Float16 half8   __attribute__((ext_vector_type(8)));
typedef float    floatx4 __attribute__((ext_vector_type(4)));

#define GLOAD_LDS16(g, l) \
    __builtin_amdgcn_global_load_lds((const __attribute__((address_space(1))) void*)(g), \
                                     (__attribute__((address_space(3))) void*)(l), 16, 0, 0)
#define GLOAD_LDS4(g, l) \
    __builtin_amdgcn_global_load_lds((const __attribute__((address_space(1))) void*)(g), \
                                     (__attribute__((address_space(3))) void*)(l), 4, 0, 0)

// ---------------- prep: codebook -> f16 hi/lo split in FRAGMENT ORDER + (-0.5*|e|^2) ----
// 128-code chunks: chunk=k>>7, step=(k&127)>>4, l15=k&15;
// slot = chunk*512 + step*64 + l4*16 + l15 (8 halves = 16 B per slot).
__global__ __launch_bounds__(64) void vq_prep(
    const float* __restrict__ cb, float* __restrict__ nhb,
    _Float16* __restrict__ Eh, _Float16* __restrict__ El)
{
    const int k = blockIdx.x * 64 + threadIdx.x;   // code id
    const float4* e4 = reinterpret_cast<const float4*>(cb) + (size_t)k * 8;
    float v[DIM];
    float4 t[8];
#pragma unroll
    for (int j = 0; j < 8; ++j) t[j] = e4[j];
#pragma unroll
    for (int j = 0; j < 8; ++j) {
        v[4 * j + 0] = t[j].x; v[4 * j + 1] = t[j].y;
        v[4 * j + 2] = t[j].z; v[4 * j + 3] = t[j].w;
    }
    float e2 = 0.0f;
#pragma unroll
    for (int i = 0; i < DIM; ++i) e2 = fmaf(v[i], v[i], e2);   // sequential: matches rescore
    nhb[k] = -0.5f * e2;

    const int chunk = k >> 7, within = k & 127;
    const int step = within >> 4, l15 = within & 15;
#pragma unroll
    for (int l4 = 0; l4 < 4; ++l4) {
        half8 h, lo;
#pragma unroll
        for (int j = 0; j < 8; ++j) {
            float x = v[l4 * 8 + j];
            _Float16 hh = (_Float16)x;
            h[j]  = hh;
            lo[j] = (_Float16)(x - (float)hh);
        }
        const int slot = chunk * 512 + step * 64 + l4 * 16 + l15;
        *reinterpret_cast<half8*>(Eh + (size_t)slot * 8) = h;
        *reinterpret_cast<half8*>(El + (size_t)slot * 8) = lo;
    }
}

// ---------------- main: m=1 max-wave-supply MFMA argmax + low-VGPR fused rescore -------
// 2048 blocks x 256 thr (4 waves); wave owns 16 tokens (m=1) -> 8192 waves total =
// 32 waves/CU = 8/SIMD at natural VGPR<=64 (no forced launch bounds -> no spills).
// 8 chunks x 128 codes; LDS ~17.3 KB -> 8 blocks/CU.
__global__ __launch_bounds__(256) void vq_main(
    const float* __restrict__ w, const float* __restrict__ c,
    const float* __restrict__ nhb, const _Float16* __restrict__ Eh,
    const _Float16* __restrict__ El, const float* __restrict__ cb,
    int* __restrict__ out)
{
    __shared__ _Float16 sEh[512 * 8];   // 8 KB: [step(8)][lane(64)][8 halves]
    __shared__ _Float16 sEl[512 * 8];   // 8 KB
    __shared__ float    snh[CCODES];    // 512 B
    __shared__ int      sOut[64];       // 256 B
    __shared__ float    sXf[4][DIM];    // 512 B per-wave rescore scratch

    const int tid  = threadIdx.x;
    const int lane = tid & 63;
    const int wid  = tid >> 6;                     // 0..3
    const int tokw = blockIdx.x * 64 + wid * 16;   // 16 tokens per wave
    const int l15  = lane & 15;
    const int l4   = lane >> 4;

    // A fragment: 1 tile of 16 tokens. A[row=l15][k=l4*8+j]; exact x = xh + xl
    half8 xh, xl;
    {
        const int token = tokw + l15;
        const float4* pw = reinterpret_cast<const float4*>(w + (size_t)token * DIM + l4 * 8);
        const float4* pc = reinterpret_cast<const float4*>(c + (size_t)token * DIM + l4 * 8);
        float4 a0 = pw[0], a1 = pw[1], b0 = pc[0], b1 = pc[1];
        float xs[8] = {a0.x - b0.x, a0.y - b0.y, a0.z - b0.z, a0.w - b0.w,
                       a1.x - b1.x, a1.y - b1.y, a1.z - b1.z, a1.w - b1.w};
#pragma unroll
        for (int j = 0; j < 8; ++j) {
            _Float16 h = (_Float16)xs[j];
            xh[j] = h;
            xl[j] = (_Float16)(xs[j] - (float)h);
        }
    }

    const float NEGINF = __uint_as_float(0xFF800000u);
    float best[4], second[4];
#pragma unroll
    for (int q = 0; q < 4; ++q) { best[q] = NEGINF; second[q] = NEGINF; }

    for (int ch = 0; ch < 8; ++ch) {
        if (ch) __syncthreads();   // all waves done reading previous chunk before overwrite
        {   // stage 128 codes (hi+lo, 16 KB) + snh (512 B), all-linear async global->LDS
            const _Float16* gh = Eh + (size_t)ch * 4096;
            const _Float16* gl = El + (size_t)ch * 4096;
#pragma unroll
            for (int r2 = 0; r2 < 2; ++r2) {
                const int slot = r2 * 256 + wid * 64;   // wave-uniform base
                GLOAD_LDS16(gh + (size_t)(slot + lane) * 8, sEh + (size_t)slot * 8);
                GLOAD_LDS16(gl + (size_t)(slot + lane) * 8, sEl + (size_t)slot * 8);
            }
            if (wid < 2) GLOAD_LDS4(nhb + ch * CCODES + wid * 64 + lane, snh + wid * 64);
        }
        __syncthreads();   // drain -> staged data visible

        // 8 steps of 16 codes, in pairs (med3 second-tracking)
#pragma unroll
        for (int sp = 0; sp < 4; ++sp) {
            const int sA = 2 * sp, sB = 2 * sp + 1;
            const half8 ehA = *reinterpret_cast<const half8*>(sEh + (size_t)(sA * 64 + lane) * 8);
            const half8 elA = *reinterpret_cast<const half8*>(sEl + (size_t)(sA * 64 + lane) * 8);
            const half8 ehB = *reinterpret_cast<const half8*>(sEh + (size_t)(sB * 64 + lane) * 8);
            const half8 elB = *reinterpret_cast<const half8*>(sEl + (size_t)(sB * 64 + lane) * 8);
            const float nhA = snh[sA * 16 + l15];
            const float nhB = snh[sB * 16 + l15];
            const unsigned ixA = 1023u - (unsigned)(ch * CCODES + sA * 16 + l15);
            const unsigned ixB = ixA - 16u;
            const floatx4 nA = {nhA, nhA, nhA, nhA};
            const floatx4 nB = {nhB, nhB, nhB, nhB};
            floatx4 aA = __builtin_amdgcn_mfma_f32_16x16x32_f16(xh, ehA, nA, 0, 0, 0);
            aA = __builtin_amdgcn_mfma_f32_16x16x32_f16(xl, ehA, aA, 0, 0, 0);
            aA = __builtin_amdgcn_mfma_f32_16x16x32_f16(xh, elA, aA, 0, 0, 0);
            floatx4 aB = __builtin_amdgcn_mfma_f32_16x16x32_f16(xh, ehB, nB, 0, 0, 0);
            aB = __builtin_amdgcn_mfma_f32_16x16x32_f16(xl, ehB, aB, 0, 0, 0);
            aB = __builtin_amdgcn_mfma_f32_16x16x32_f16(xh, elB, aB, 0, 0, 0);
#pragma unroll
            for (int r = 0; r < 4; ++r) {
                float pA = __uint_as_float((__float_as_uint(aA[r]) & 0xFFFFFC00u) | ixA);
                float pB = __uint_as_float((__float_as_uint(aB[r]) & 0xFFFFFC00u) | ixB);
                second[r] = fmaxf(second[r], __builtin_amdgcn_fmed3f(pA, pB, best[r]));
                best[r]   = fmaxf(fmaxf(best[r], pA), pB);
            }
        }
    }

    // reduce across the 16 code-lanes (xor over lane bits 0..3)
#pragma unroll
    for (int sh = 1; sh < 16; sh <<= 1) {
#pragma unroll
        for (int q = 0; q < 4; ++q) {
            float bB = __shfl_xor(best[q], sh);
            float sB = __shfl_xor(second[q], sh);
            second[q] = fmaxf(fmaxf(second[q], sB), fminf(best[q], bB));
            best[q]   = fmaxf(best[q], bB);
        }
    }

    // stage per-token results (k | optional FLAGBIT) -- R12's proven threshold
    if (l15 == 0) {
#pragma unroll
        for (int r = 0; r < 4; ++r) {
            unsigned ub = __float_as_uint(best[r]);
            unsigned us = __float_as_uint(second[r]);
            float bv = __uint_as_float(ub & 0xFFFFFC00u);
            float sv = __uint_as_float(us & 0xFFFFFC00u);
            int eb = (int)((ub >> 23) & 255u);
            int es = (int)((us >> 23) & 255u);
            int em = eb > es ? eb : es;
            em = em > 12 ? em : 12;
            // flag threshold = 4 * packing granule + eps (covers split-f16 error)
            float thr = __uint_as_float((unsigned)(em - 11) << 23) + DELTA_EPS;
            int k = 1023 - (int)(ub & 1023u);
            sOut[wid * 16 + l4 * 4 + r] = ((bv - sv) < thr) ? (k | FLAGBIT) : k;
        }
    }

    // lane i (<16) owns token tokw+i; rescore flagged tokens exactly (wave-cooperative).
    // LOW-VGPR path (R18-proven): x staged in per-wave LDS, codebook streamed float4-wise.
    int myval = 0;
    if (lane < 16) myval = sOut[wid * 16 + lane];
    unsigned long long mask = __ballot(lane < 16 && (myval & FLAGBIT));
    while (mask) {
        const int src = __ffsll(mask) - 1;
        mask &= mask - 1;
        const int token = tokw + src;   // wave-uniform

        if (lane < DIM)
            sXf[wid][lane] = w[(size_t)token * DIM + lane] - c[(size_t)token * DIM + lane];
        // LDS ops within a wave complete in order; compiler inserts lgkmcnt before reads.

        float x2 = 0.f;
#pragma unroll
        for (int i = 0; i < DIM; ++i) x2 = fmaf(sXf[wid][i], sXf[wid][i], x2);

        float dmin = INFINITY;
        int   kbest = 0;
        for (int i = 0; i < 16; ++i) {
            const int k = lane + 64 * i;           // ascending per lane
            const float4* e4 = reinterpret_cast<const float4*>(cb) + (size_t)k * 8;
            float dot = 0.f;
#pragma unroll
            for (int j = 0; j < 8; ++j) {          // sequential order: j*4+0..3
                float4 ev = e4[j];
                dot = fmaf(sXf[wid][4 * j + 0], ev.x, dot);
                dot = fmaf(sXf[wid][4 * j + 1], ev.y, dot);
                dot = fmaf(sXf[wid][4 * j + 2], ev.z, dot);
                dot = fmaf(sXf[wid][4 * j + 3], ev.w, dot);
            }
            float e2 = -2.0f * nhb[k];             // bit-exact |e|^2 (seq-fma in prep)
            float dd = fmaf(-2.0f, dot, x2) + e2;
            if (dd < dmin) { dmin = dd; kbest = k; }
        }
#pragma unroll
        for (int sh = 1; sh < 64; sh <<= 1) {
            float dB = __shfl_xor(dmin, sh);
            int   iB = __shfl_xor(kbest, sh);
            bool take = (dB < dmin) || (dB == dmin && iB < kbest);
            dmin = take ? dB : dmin;
            kbest = take ? iB : kbest;
        }
        if (lane == src) myval = kbest;   // exact index, flag cleared
    }
    if (lane < 16) out[tokw + lane] = myval;   // coalesced 64 B per wave
}

extern "C" void kernel_launch(void* const* d_in, const int* in_sizes, int n_in,
                              void* d_out, int out_size, void* d_ws, size_t ws_size,
                              hipStream_t stream) {
    const float* w  = (const float*)d_in[0];   // weights   [4194304]
    const float* c  = (const float*)d_in[1];   // condition [1,32,131072] flat
    const float* cb = (const float*)d_in[2];   // codebook  [1024,32]
    int* out = (int*)d_out;                    // int32 indices [131072]

    char* wsb = (char*)d_ws;
    float*    nhb = (float*)wsb;                       // 4 KB
    _Float16* Eh  = (_Float16*)(wsb + 4096);           // 64 KB (fragment-ordered)
    _Float16* El  = (_Float16*)(wsb + 4096 + 65536);   // 64 KB (fragment-ordered)

    vq_prep<<<NCODE / 64, 64, 0, stream>>>(cb, nhb, Eh, El);
    vq_main<<<NTOK / 64, 256, 0, stream>>>(w, c, nhb, Eh, El, cb, out);
}